// Round 1
// baseline (4656.870 us; speedup 1.0000x reference)
//
#include <hip/hip_runtime.h>
#include <math.h>

#define NN 25000
#define NE 400000
#define TD 416
#define BLK 128

__device__ __forceinline__ float silu_f(float x) {
    return x * (1.0f / (1.0f + __expf(-x)));
}

// ---------------- zero output ----------------
__global__ void zero_out_k(float* __restrict__ out, int n) {
    int n4 = n >> 2;
    float4 z = make_float4(0.f, 0.f, 0.f, 0.f);
    float4* o4 = (float4*)out;
    for (int i = blockIdx.x * blockDim.x + threadIdx.x; i < n4;
         i += gridDim.x * blockDim.x)
        o4[i] = z;
    // tail (out_size is divisible by 4 here, but be safe)
    if (blockIdx.x == 0 && threadIdx.x < (n & 3)) out[(n4 << 2) + threadIdx.x] = 0.f;
}

// ---------------- node scalar MLP: Ai = silu(emb[A] @ w1 + b1) @ w2 + b2 ----------------
__global__ void node_mlp(const int* __restrict__ A,
                         const float* __restrict__ emb_table,
                         const float* __restrict__ w1, const float* __restrict__ b1,
                         const float* __restrict__ w2, const float* __restrict__ b2,
                         float* __restrict__ Ai) {
    __shared__ float s_w1[16 * 64];
    __shared__ float s_b1[64];
    __shared__ float s_w2[64 * 8];
    __shared__ float s_b2[8];
    for (int i = threadIdx.x; i < 16 * 64; i += blockDim.x) s_w1[i] = w1[i];
    for (int i = threadIdx.x; i < 64; i += blockDim.x) s_b1[i] = b1[i];
    for (int i = threadIdx.x; i < 64 * 8; i += blockDim.x) s_w2[i] = w2[i];
    for (int i = threadIdx.x; i < 8; i += blockDim.x) s_b2[i] = b2[i];
    __syncthreads();
    int n = blockIdx.x * blockDim.x + threadIdx.x;
    if (n >= NN) return;
    int a = A[n];
    float e[16];
#pragma unroll
    for (int i = 0; i < 16; ++i) e[i] = emb_table[a * 16 + i];
    float acc[8];
#pragma unroll
    for (int o = 0; o < 8; ++o) acc[o] = s_b2[o];
#pragma unroll 1
    for (int j = 0; j < 64; ++j) {
        float h = s_b1[j];
#pragma unroll
        for (int i = 0; i < 16; ++i) h += e[i] * s_w1[i * 64 + j];
        h = silu_f(h);
#pragma unroll
        for (int o = 0; o < 8; ++o) acc[o] += h * s_w2[j * 8 + o];
    }
#pragma unroll
    for (int o = 0; o < 8; ++o) Ai[n * 8 + o] = acc[o];
}

// ---------------- per-edge: geometry + basis + radial MLP + TP + atomic scatter ----------------
__global__ __launch_bounds__(BLK) void edge_conv(
    const float* __restrict__ pos,
    const int* __restrict__ batch,
    const int* __restrict__ esrc,
    const int* __restrict__ edst,
    const float* __restrict__ shifts,
    const float* __restrict__ cell,
    const float* __restrict__ fw1, const float* __restrict__ fb1,
    const float* __restrict__ fw2, const float* __restrict__ fb2,
    const float* __restrict__ fw3, const float* __restrict__ fb3,
    const float* __restrict__ Ai,
    float* __restrict__ out) {
    __shared__ float s_w1[8 * 64];    // 2 KB
    __shared__ float s_b1[64];
    __shared__ float s_w2[64 * 64];   // 16 KB
    __shared__ float s_b2[64];
    __shared__ float s_h[64 * BLK];   // 32 KB: per-thread private hidden column

    for (int i = threadIdx.x; i < 8 * 64; i += BLK) s_w1[i] = fw1[i];
    for (int i = threadIdx.x; i < 64; i += BLK) { s_b1[i] = fb1[i]; s_b2[i] = fb2[i]; }
    for (int i = threadIdx.x; i < 64 * 64; i += BLK) s_w2[i] = fw2[i];
    __syncthreads();

    const int e = blockIdx.x * BLK + threadIdx.x;
    if (e >= NE) return;
    const int tid = threadIdx.x;

    // ---- geometry ----
    const int src = esrc[e];
    const int dst = edst[e];
    const int b = batch[src];
    const float* cb = cell + b * 9;
    const float sh0 = shifts[e * 3 + 0], sh1 = shifts[e * 3 + 1], sh2 = shifts[e * 3 + 2];
    float vx = pos[dst * 3 + 0] - pos[src * 3 + 0] + sh0 * cb[0] + sh1 * cb[3] + sh2 * cb[6];
    float vy = pos[dst * 3 + 1] - pos[src * 3 + 1] + sh0 * cb[1] + sh1 * cb[4] + sh2 * cb[7];
    float vz = pos[dst * 3 + 2] - pos[src * 3 + 2] + sh0 * cb[2] + sh1 * cb[5] + sh2 * cb[8];
    const float len = sqrtf(vx * vx + vy * vy + vz * vz + 1e-12f);
    const float il = 1.0f / len;
    const float ux = vx * il, uy = vy * il, uz = vz * il;

    // ---- radial basis: gaussian soft-one-hot * sqrt(NB) ----
    float emb[8];
#pragma unroll
    for (int k = 0; k < 8; ++k) {
        float d = (len - (5.0f * (float)(k + 1) / 9.0f)) * 1.8f;  // /(5/9)
        emb[k] = __expf(-d * d) * 2.525381361380528f;             // sqrt(8)/1.12
    }

    // ---- layer 1: 8 -> 64 (write h1 into private LDS column) ----
#pragma unroll 1
    for (int j = 0; j < 64; ++j) {
        float a = s_b1[j];
#pragma unroll
        for (int k = 0; k < 8; ++k) a += emb[k] * s_w1[k * 64 + j];
        s_h[j * BLK + tid] = silu_f(a);
    }

    // ---- layer 2: 64 -> 64 (accumulate in regs, overwrite LDS column) ----
    float h2a[64];
#pragma unroll
    for (int j = 0; j < 64; ++j) h2a[j] = s_b2[j];
#pragma unroll 1
    for (int k = 0; k < 64; ++k) {
        const float hk = s_h[k * BLK + tid];
        const float4* w2r = (const float4*)(s_w2 + k * 64);
#pragma unroll
        for (int j4 = 0; j4 < 16; ++j4) {
            float4 wv = w2r[j4];
            h2a[j4 * 4 + 0] += hk * wv.x;
            h2a[j4 * 4 + 1] += hk * wv.y;
            h2a[j4 * 4 + 2] += hk * wv.z;
            h2a[j4 * 4 + 3] += hk * wv.w;
        }
    }
#pragma unroll
    for (int j = 0; j < 64; ++j) s_h[j * BLK + tid] = silu_f(h2a[j]);

    // ---- Ai of source node ----
    const float4* aiv = (const float4*)(Ai + src * 8);
    const float4 a0 = aiv[0], a1 = aiv[1];
    const float Aic[8] = {a0.x, a0.y, a0.z, a0.w, a1.x, a1.y, a1.z, a1.w};

    // ---- layer 3 fused with Ai contraction:
    // s[l][o] = sum_c Ai[c]*b3[l,c,o] + sum_k h2[k] * sum_c Ai[c]*W3[k][l,c,o] ----
    const float4* w3v = (const float4*)fw3;  // [64][96] float4, idx k*96 + l*32 + c*4 + o4
    const float4* b3v = (const float4*)fb3;  // [96]
    float4 sacc[12];                         // [l][o4]
#pragma unroll
    for (int l = 0; l < 3; ++l) {
#pragma unroll
        for (int o4 = 0; o4 < 4; ++o4) {
            float4 a = make_float4(0.f, 0.f, 0.f, 0.f);
#pragma unroll
            for (int c = 0; c < 8; ++c) {
                float4 wv = b3v[l * 32 + c * 4 + o4];
                a.x += Aic[c] * wv.x; a.y += Aic[c] * wv.y;
                a.z += Aic[c] * wv.z; a.w += Aic[c] * wv.w;
            }
            sacc[l * 4 + o4] = a;
        }
    }
#pragma unroll 1
    for (int k = 0; k < 64; ++k) {
        const float hk = s_h[k * BLK + tid];
        float m[8];
#pragma unroll
        for (int c = 0; c < 8; ++c) m[c] = hk * Aic[c];
        const float4* wr = w3v + k * 96;
#pragma unroll
        for (int l = 0; l < 3; ++l) {
#pragma unroll
            for (int c = 0; c < 8; ++c) {
                const float mc = m[c];
#pragma unroll
                for (int o4 = 0; o4 < 4; ++o4) {
                    float4 wv = wr[l * 32 + c * 4 + o4];
                    float4 s = sacc[l * 4 + o4];
                    s.x += mc * wv.x; s.y += mc * wv.y;
                    s.z += mc * wv.z; s.w += mc * wv.w;
                    sacc[l * 4 + o4] = s;
                }
            }
        }
    }

    // ---- epilogue: fold 1/avg_num_neighbors (=1/16), outer products, atomic scatter ----
    const float SC = (float)NN / (float)NE;  // 0.0625
    float s0[16], s1[16], s2[16];
#pragma unroll
    for (int o4 = 0; o4 < 4; ++o4) {
        float4 v0 = sacc[o4], v1 = sacc[4 + o4], v2 = sacc[8 + o4];
        s0[o4 * 4 + 0] = v0.x * SC; s0[o4 * 4 + 1] = v0.y * SC;
        s0[o4 * 4 + 2] = v0.z * SC; s0[o4 * 4 + 3] = v0.w * SC;
        s1[o4 * 4 + 0] = v1.x * SC; s1[o4 * 4 + 1] = v1.y * SC;
        s1[o4 * 4 + 2] = v1.z * SC; s1[o4 * 4 + 3] = v1.w * SC;
        s2[o4 * 4 + 0] = v2.x * SC; s2[o4 * 4 + 1] = v2.y * SC;
        s2[o4 * 4 + 2] = v2.z * SC; s2[o4 * 4 + 3] = v2.w * SC;
    }
    float* op = out + (size_t)dst * TD;
#pragma unroll
    for (int o = 0; o < 16; ++o) unsafeAtomicAdd(op + o, s0[o]);
#pragma unroll
    for (int o = 0; o < 16; ++o) {
        unsafeAtomicAdd(op + 16 + o * 3 + 0, s1[o] * ux);
        unsafeAtomicAdd(op + 16 + o * 3 + 1, s1[o] * uy);
        unsafeAtomicAdd(op + 16 + o * 3 + 2, s1[o] * uz);
    }
    const float uu[9] = {ux * ux, ux * uy, ux * uz,
                         uy * ux, uy * uy, uy * uz,
                         uz * ux, uz * uy, uz * uz};
#pragma unroll
    for (int o = 0; o < 16; ++o) {
#pragma unroll
        for (int ij = 0; ij < 9; ++ij)
            unsafeAtomicAdd(op + 64 + o * 9 + ij, s2[o] * uu[ij]);
    }
}

extern "C" void kernel_launch(void* const* d_in, const int* in_sizes, int n_in,
                              void* d_out, int out_size, void* d_ws, size_t ws_size,
                              hipStream_t stream) {
    const float* pos       = (const float*)d_in[0];
    const int*   A         = (const int*)d_in[1];
    const int*   batch     = (const int*)d_in[2];
    const int*   esrc      = (const int*)d_in[3];
    const int*   edst      = (const int*)d_in[4];
    const float* shifts    = (const float*)d_in[5];
    const float* cell      = (const float*)d_in[6];
    const float* emb_table = (const float*)d_in[7];
    const float* aw1       = (const float*)d_in[8];
    const float* ab1       = (const float*)d_in[9];
    const float* aw2       = (const float*)d_in[10];
    const float* ab2       = (const float*)d_in[11];
    const float* fw1       = (const float*)d_in[12];
    const float* fb1       = (const float*)d_in[13];
    const float* fw2       = (const float*)d_in[14];
    const float* fb2       = (const float*)d_in[15];
    const float* fw3       = (const float*)d_in[16];
    const float* fb3       = (const float*)d_in[17];
    float* out = (float*)d_out;
    float* Ai  = (float*)d_ws;  // [NN, 8] fp32 = 800 KB

    zero_out_k<<<2048, 256, 0, stream>>>(out, out_size);
    node_mlp<<<(NN + 255) / 256, 256, 0, stream>>>(A, emb_table, aw1, ab1, aw2, ab2, Ai);
    edge_conv<<<(NE + BLK - 1) / BLK, BLK, 0, stream>>>(
        pos, batch, esrc, edst, shifts, cell,
        fw1, fb1, fw2, fb2, fw3, fb3, Ai, out);
}

// Round 2
// 465.915 us; speedup vs baseline: 9.9951x; 9.9951x over previous
//
#include <hip/hip_runtime.h>
#include <math.h>

#define NN 25000
#define NE 400000
#define TD 416
#define BT 128                 // edge_k block (threads = edges per block)
#define NBLK_E 3135            // NE/BT + 10 (type-padded tlist regions)
#define NT_LIST (NBLK_E * BT)  // 401280
#define GB 256                 // gather block

__device__ __forceinline__ float silu_f(float x) {
    return x * (1.0f / (1.0f + __expf(-x)));
}

// ---------- ws init: tlist=-1, counters=0 ----------
__global__ void init_k(int* __restrict__ tlist, int* __restrict__ cnt_dst,
                       int* __restrict__ cnt_t) {
    int i = blockIdx.x * blockDim.x + threadIdx.x;
    for (int k = i; k < NT_LIST; k += gridDim.x * blockDim.x) tlist[k] = -1;
    for (int k = i; k < NN + 1; k += gridDim.x * blockDim.x) cnt_dst[k] = 0;
    if (i < 16) cnt_t[i] = 0;
}

// ---------- per-atom-type scalar features Ai_t[10][8] ----------
__global__ void precomp1(const float* __restrict__ emb_table,
                         const float* __restrict__ aw1, const float* __restrict__ ab1,
                         const float* __restrict__ aw2, const float* __restrict__ ab2,
                         float* __restrict__ Ai_t) {
    int t = threadIdx.x;
    if (t >= 10) return;
    float acc[8];
#pragma unroll
    for (int o = 0; o < 8; ++o) acc[o] = ab2[o];
    for (int j = 0; j < 64; ++j) {
        float h = ab1[j];
#pragma unroll
        for (int i = 0; i < 16; ++i) h += emb_table[t * 16 + i] * aw1[i * 64 + j];
        h = silu_f(h);
#pragma unroll
        for (int o = 0; o < 8; ++o) acc[o] += h * aw2[j * 8 + o];
    }
#pragma unroll
    for (int o = 0; o < 8; ++o) Ai_t[t * 8 + o] = acc[o];
}

// ---------- type-contracted layer-3 weights: W3t[t][k][l*16+o], b3t[t][l*16+o] ----------
__global__ void precomp2(const float* __restrict__ fw3, const float* __restrict__ fb3,
                         const float* __restrict__ Ai_t,
                         float* __restrict__ W3t, float* __restrict__ b3t) {
    int idx = blockIdx.x * blockDim.x + threadIdx.x;
    if (idx < 10 * 64 * 48) {
        int t = idx / (64 * 48);
        int rem = idx - t * 64 * 48;
        int k = rem / 48;
        int lo = rem - k * 48;
        int l = lo >> 4, o = lo & 15;
        float s = 0.f;
#pragma unroll
        for (int c = 0; c < 8; ++c)
            s += Ai_t[t * 8 + c] * fw3[k * 384 + l * 128 + c * 16 + o];
        W3t[idx] = s;
    } else if (idx < 10 * 64 * 48 + 10 * 48) {
        int q = idx - 10 * 64 * 48;
        int t = q / 48;
        int lo = q - t * 48;
        int l = lo >> 4, o = lo & 15;
        float s = 0.f;
#pragma unroll
        for (int c = 0; c < 8; ++c) s += Ai_t[t * 8 + c] * fb3[l * 128 + c * 16 + o];
        b3t[q] = s;
    }
}

// ---------- count: per-dst rank + per-type rank (LDS-hierarchical for 10 hot counters) ----------
__global__ void count_k(const int* __restrict__ esrc, const int* __restrict__ edst,
                        const int* __restrict__ A,
                        int* __restrict__ cnt_dst, int* __restrict__ cnt_t,
                        int* __restrict__ rdst, int* __restrict__ rt) {
    __shared__ int lcnt[10];
    __shared__ int gbase[10];
    int tid = threadIdx.x;
    if (tid < 10) lcnt[tid] = 0;
    __syncthreads();
    int e = blockIdx.x * blockDim.x + tid;
    int t = 0, lr = 0;
    bool valid = e < NE;
    if (valid) {
        rdst[e] = atomicAdd(&cnt_dst[edst[e]], 1);
        t = A[esrc[e]];
        lr = atomicAdd(&lcnt[t], 1);
    }
    __syncthreads();
    if (tid < 10) gbase[tid] = atomicAdd(&cnt_t[tid], lcnt[tid]);
    __syncthreads();
    if (valid) rt[e] = gbase[t] + lr;
}

// ---------- single-block scan: off_dst (25k excl scan) + padded type offsets ----------
__global__ __launch_bounds__(1024) void scan_k(const int* __restrict__ cnt_dst,
                                               int* __restrict__ off_dst,
                                               const int* __restrict__ cnt_t,
                                               int* __restrict__ offt_pad) {
    __shared__ int s_part[1024];
    const int tid = threadIdx.x;
    const int CH = 25;  // 1024*25 = 25600 >= 25000
    int base = tid * CH;
    int sum = 0;
    for (int i = 0; i < CH; ++i) {
        int idx = base + i;
        sum += (idx < NN) ? cnt_dst[idx] : 0;
    }
    s_part[tid] = sum;
    __syncthreads();
    for (int off = 1; off < 1024; off <<= 1) {
        int v = (tid >= off) ? s_part[tid - off] : 0;
        __syncthreads();
        s_part[tid] += v;
        __syncthreads();
    }
    int run = s_part[tid] - sum;  // exclusive prefix of this chunk
    for (int i = 0; i < CH; ++i) {
        int idx = base + i;
        if (idx < NN) {
            off_dst[idx] = run;
            run += cnt_dst[idx];
        }
    }
    if (tid == 1023) off_dst[NN] = s_part[1023];
    if (tid == 0) {
        int running = 0;
        for (int t = 0; t < 10; ++t) {
            offt_pad[t] = running;
            int c = cnt_t[t];
            running += ((c + BT - 1) / BT) * BT;
        }
        offt_pad[10] = running;
    }
}

// ---------- scatter edge ids into dst-CSR list and type-bucketed (padded) list ----------
__global__ void scatter_k(const int* __restrict__ esrc, const int* __restrict__ edst,
                          const int* __restrict__ A,
                          const int* __restrict__ off_dst, const int* __restrict__ offt_pad,
                          const int* __restrict__ rdst, const int* __restrict__ rt,
                          int* __restrict__ elist, int* __restrict__ tlist) {
    int e = blockIdx.x * blockDim.x + threadIdx.x;
    if (e >= NE) return;
    elist[off_dst[edst[e]] + rdst[e]] = e;
    int t = A[esrc[e]];
    tlist[offt_pad[t] + rt[e]] = e;
}

// ---------- edge kernel: geometry + basis + radial MLP + type-contracted L3 -> payload ----------
// payload row (52 floats): [0..15]=s0*SC, [16..31]=s1*SC, [32..47]=s2*SC, [48..50]=u, [51]=pad
__global__ __launch_bounds__(BT) void edge_k(
    const int* __restrict__ tlist,
    const int* __restrict__ A,
    const int* __restrict__ esrc, const int* __restrict__ edst,
    const float* __restrict__ pos, const float* __restrict__ shifts,
    const float* __restrict__ cell, const int* __restrict__ batch,
    const float* __restrict__ fw1, const float* __restrict__ fb1,
    const float* __restrict__ fw2, const float* __restrict__ fb2,
    const float* __restrict__ W3t, const float* __restrict__ b3t,
    float* __restrict__ payload) {
    __shared__ float s_h[64 * BT];
    const int tid = threadIdx.x;
    const int slot = blockIdx.x * BT;
    const int e0 = tlist[slot];
    if (e0 < 0) return;  // fully-padded / out-of-range block
    int t_blk = A[esrc[e0]];
    t_blk = __builtin_amdgcn_readfirstlane(t_blk);  // block-uniform by construction
    const float4* Wt = (const float4*)(W3t + t_blk * 64 * 48);
    const float4* bt = (const float4*)(b3t + t_blk * 48);

    const int eid = tlist[slot + tid];
    if (eid < 0) return;  // pad tail (no barriers below)

    // ---- geometry ----
    const int src = esrc[eid], dst_n = edst[eid];
    const int b = batch[src];
    const float* cb = cell + b * 9;
    const float sh0 = shifts[eid * 3 + 0], sh1 = shifts[eid * 3 + 1], sh2 = shifts[eid * 3 + 2];
    float vx = pos[dst_n * 3 + 0] - pos[src * 3 + 0] + sh0 * cb[0] + sh1 * cb[3] + sh2 * cb[6];
    float vy = pos[dst_n * 3 + 1] - pos[src * 3 + 1] + sh0 * cb[1] + sh1 * cb[4] + sh2 * cb[7];
    float vz = pos[dst_n * 3 + 2] - pos[src * 3 + 2] + sh0 * cb[2] + sh1 * cb[5] + sh2 * cb[8];
    const float len = sqrtf(vx * vx + vy * vy + vz * vz + 1e-12f);
    const float il = 1.0f / len;
    const float ux = vx * il, uy = vy * il, uz = vz * il;

    // ---- radial basis ----
    float emb[8];
#pragma unroll
    for (int k = 0; k < 8; ++k) {
        float d = (len - (5.0f * (float)(k + 1) / 9.0f)) * 1.8f;
        emb[k] = __expf(-d * d) * 2.525381361380528f;  // sqrt(8)/1.12
    }

    // ---- layer 1: 8 -> 64 (uniform weight loads; h1 -> private LDS column) ----
    const float4* w1v = (const float4*)fw1;  // [8][16]
    const float4* b1v = (const float4*)fb1;
#pragma unroll
    for (int j4 = 0; j4 < 16; ++j4) {
        float4 a = b1v[j4];
#pragma unroll
        for (int k = 0; k < 8; ++k) {
            float4 w = w1v[k * 16 + j4];
            a.x += emb[k] * w.x; a.y += emb[k] * w.y;
            a.z += emb[k] * w.z; a.w += emb[k] * w.w;
        }
        s_h[(j4 * 4 + 0) * BT + tid] = silu_f(a.x);
        s_h[(j4 * 4 + 1) * BT + tid] = silu_f(a.y);
        s_h[(j4 * 4 + 2) * BT + tid] = silu_f(a.z);
        s_h[(j4 * 4 + 3) * BT + tid] = silu_f(a.w);
    }

    // ---- layer 2: 64 -> 64 ----
    float h2a[64];
    const float4* b2v = (const float4*)fb2;
#pragma unroll
    for (int j4 = 0; j4 < 16; ++j4) {
        float4 v = b2v[j4];
        h2a[4 * j4 + 0] = v.x; h2a[4 * j4 + 1] = v.y;
        h2a[4 * j4 + 2] = v.z; h2a[4 * j4 + 3] = v.w;
    }
    const float4* w2v = (const float4*)fw2;  // [64][16]
#pragma unroll 2
    for (int k = 0; k < 64; ++k) {
        const float hk = s_h[k * BT + tid];
#pragma unroll
        for (int j4 = 0; j4 < 16; ++j4) {
            float4 w = w2v[k * 16 + j4];
            h2a[4 * j4 + 0] += hk * w.x; h2a[4 * j4 + 1] += hk * w.y;
            h2a[4 * j4 + 2] += hk * w.z; h2a[4 * j4 + 3] += hk * w.w;
        }
    }
#pragma unroll
    for (int j = 0; j < 64; ++j) s_h[j * BT + tid] = silu_f(h2a[j]);

    // ---- layer 3 (type-contracted): s[48] = b3t + h2 @ W3t[type] ----
    float s[48];
#pragma unroll
    for (int q = 0; q < 12; ++q) {
        float4 v = bt[q];
        s[4 * q + 0] = v.x; s[4 * q + 1] = v.y; s[4 * q + 2] = v.z; s[4 * q + 3] = v.w;
    }
#pragma unroll 2
    for (int k = 0; k < 64; ++k) {
        const float hk = s_h[k * BT + tid];
#pragma unroll
        for (int q = 0; q < 12; ++q) {
            float4 w = Wt[k * 12 + q];
            s[4 * q + 0] += hk * w.x; s[4 * q + 1] += hk * w.y;
            s[4 * q + 2] += hk * w.z; s[4 * q + 3] += hk * w.w;
        }
    }

    // ---- store payload (edge-order, dense/coalesced-ish) ----
    const float SC = (float)NN / (float)NE;  // 1/16
    float4* pv = (float4*)(payload + (size_t)eid * 52);
#pragma unroll
    for (int q = 0; q < 12; ++q)
        pv[q] = make_float4(s[4 * q + 0] * SC, s[4 * q + 1] * SC,
                            s[4 * q + 2] * SC, s[4 * q + 3] * SC);
    pv[12] = make_float4(ux, uy, uz, 0.f);
}

// ---------- gather: one block per node, expand outer products, single write per output ----------
__global__ __launch_bounds__(GB) void gather_k(const int* __restrict__ off_dst,
                                               const int* __restrict__ elist,
                                               const float* __restrict__ payload,
                                               float* __restrict__ out) {
    __shared__ float sp[8][52];
    const int n = blockIdx.x;
    const int tid = threadIdx.x;
    const int lo = off_dst[n], hi = off_dst[n + 1];
    int kind = 3, c = 0, ui = 0, uj = 0;
    if (tid < 16) { kind = 0; c = tid; }
    else if (tid < 64) { int q = tid - 16; kind = 1; c = q / 3; ui = q % 3; }
    else if (tid < 208) { int q = tid - 64; kind = 2; c = q / 9; int ij = q % 9; ui = ij / 3; uj = ij % 3; }
    float acc = 0.f;
    for (int p0 = lo; p0 < hi; p0 += 8) {
        int m = min(8, hi - p0);
        for (int idx = tid; idx < m * 52; idx += GB) {
            int r = idx / 52, ii = idx - r * 52;
            int eid = elist[p0 + r];
            sp[r][ii] = payload[(size_t)eid * 52 + ii];
        }
        __syncthreads();
        for (int r = 0; r < m; ++r) {
            if (kind == 0) acc += sp[r][c];
            else if (kind == 1) acc += sp[r][16 + c] * sp[r][48 + ui];
            else if (kind == 2) acc += sp[r][32 + c] * sp[r][48 + ui] * sp[r][48 + uj];
        }
        __syncthreads();
    }
    if (tid < 208) {
        out[(size_t)n * TD + tid] = acc;
        out[(size_t)n * TD + 208 + tid] = 0.f;
    }
}

extern "C" void kernel_launch(void* const* d_in, const int* in_sizes, int n_in,
                              void* d_out, int out_size, void* d_ws, size_t ws_size,
                              hipStream_t stream) {
    const float* pos       = (const float*)d_in[0];
    const int*   A         = (const int*)d_in[1];
    const int*   batch     = (const int*)d_in[2];
    const int*   esrc      = (const int*)d_in[3];
    const int*   edst      = (const int*)d_in[4];
    const float* shifts    = (const float*)d_in[5];
    const float* cell      = (const float*)d_in[6];
    const float* emb_table = (const float*)d_in[7];
    const float* aw1       = (const float*)d_in[8];
    const float* ab1       = (const float*)d_in[9];
    const float* aw2       = (const float*)d_in[10];
    const float* ab2       = (const float*)d_in[11];
    const float* fw1       = (const float*)d_in[12];
    const float* fb1       = (const float*)d_in[13];
    const float* fw2       = (const float*)d_in[14];
    const float* fb2       = (const float*)d_in[15];
    const float* fw3       = (const float*)d_in[16];
    const float* fb3       = (const float*)d_in[17];
    float* out = (float*)d_out;

    // ---- ws layout (~90 MB) ----
    float* W3t  = (float*)d_ws;            // 30720
    float* b3t  = W3t + 30720;             // 480
    float* Ai_t = b3t + 480;               // 80
    int* cnt_dst  = (int*)(Ai_t + 80);     // 25008 (padded)
    int* off_dst  = cnt_dst + 25008;       // 25008
    int* cnt_t    = off_dst + 25008;       // 16
    int* offt_pad = cnt_t + 16;            // 16
    int* rdst  = offt_pad + 16;            // 400000
    int* rt    = rdst + 400000;            // 400000
    int* elist = rt + 400000;              // 400000
    int* tlist = elist + 400000;           // 401280
    float* payload = (float*)(tlist + NT_LIST);  // 400000*52 floats (16B-aligned)

    init_k<<<512, 256, 0, stream>>>(tlist, cnt_dst, cnt_t);
    precomp1<<<1, 64, 0, stream>>>(emb_table, aw1, ab1, aw2, ab2, Ai_t);
    precomp2<<<(10 * 64 * 48 + 10 * 48 + 255) / 256, 256, 0, stream>>>(fw3, fb3, Ai_t, W3t, b3t);
    count_k<<<(NE + 255) / 256, 256, 0, stream>>>(esrc, edst, A, cnt_dst, cnt_t, rdst, rt);
    scan_k<<<1, 1024, 0, stream>>>(cnt_dst, off_dst, cnt_t, offt_pad);
    scatter_k<<<(NE + 255) / 256, 256, 0, stream>>>(esrc, edst, A, off_dst, offt_pad,
                                                    rdst, rt, elist, tlist);
    edge_k<<<NBLK_E, BT, 0, stream>>>(tlist, A, esrc, edst, pos, shifts, cell, batch,
                                      fw1, fb1, fw2, fb2, W3t, b3t, payload);
    gather_k<<<NN, GB, 0, stream>>>(off_dst, elist, payload, out);
}

// Round 3
// 310.027 us; speedup vs baseline: 15.0209x; 1.5028x over previous
//
#include <hip/hip_runtime.h>
#include <math.h>

#define NN 25000
#define NE 400000
#define TD 416
#define NBLK64 6260            // NE/64 + 10 type-padding blocks
#define NT_LIST (NBLK64 * 64)  // 400640
#define PLS 52                 // payload row stride (floats), 208B = 13x16B
#define GB 256

typedef __attribute__((ext_vector_type(8))) __bf16 bf16x8;
typedef __attribute__((ext_vector_type(4))) __bf16 bf16x4;
typedef __attribute__((ext_vector_type(4))) float f32x4;

__device__ __forceinline__ float silu_f(float x) {
    return x * (1.0f / (1.0f + __expf(-x)));
}

// ---------- wsprep: Ai_t + MFMA-layout bf16 weights (A = W^T fragments) ----------
// w1a[m][lane][j]  : 2048 bf16  (K=32 padded; k=8 row = bias, k>8 = 0)
// w2a[(m*2+kt)][lane][j] : 4096 bf16
// w3ta[((t*3+m)*2+kt)][lane][j] : 30720 bf16
// b3t[t][48] fp32
__global__ __launch_bounds__(256) void wsprep(
    const float* __restrict__ emb_table,
    const float* __restrict__ aw1, const float* __restrict__ ab1,
    const float* __restrict__ aw2, const float* __restrict__ ab2,
    const float* __restrict__ fw1, const float* __restrict__ fb1,
    const float* __restrict__ fw2,
    const float* __restrict__ fw3, const float* __restrict__ fb3,
    __bf16* __restrict__ w1a, __bf16* __restrict__ w2a,
    __bf16* __restrict__ w3ta, float* __restrict__ b3t) {
    __shared__ float s_ai[80];
    const int tid = threadIdx.x;
    if (tid < 10) {
        float acc[8];
#pragma unroll
        for (int o = 0; o < 8; ++o) acc[o] = ab2[o];
        for (int j = 0; j < 64; ++j) {
            float h = ab1[j];
#pragma unroll
            for (int i = 0; i < 16; ++i) h += emb_table[tid * 16 + i] * aw1[i * 64 + j];
            h = silu_f(h);
#pragma unroll
            for (int o = 0; o < 8; ++o) acc[o] += h * aw2[j * 8 + o];
        }
#pragma unroll
        for (int o = 0; o < 8; ++o) s_ai[tid * 8 + o] = acc[o];
    }
    __syncthreads();
    for (int i = blockIdx.x * 256 + tid; i < 37344; i += 64 * 256) {
        if (i < 2048) {
            int m = i >> 9, r = i & 511, lane = r >> 3, j = r & 7;
            int k = (lane >> 4) * 8 + j, ch = m * 16 + (lane & 15);
            float v = (k < 8) ? fw1[k * 64 + ch] : ((k == 8) ? fb1[ch] : 0.0f);
            w1a[i] = (__bf16)v;
        } else if (i < 6144) {
            int q = i - 2048;
            int mk = q >> 9, lane = (q >> 3) & 63, j = q & 7;
            int m = mk >> 1, kt = mk & 1;
            int k = kt * 32 + (lane >> 4) * 8 + j, ch = m * 16 + (lane & 15);
            w2a[q] = (__bf16)fw2[k * 64 + ch];
        } else if (i < 36864) {
            int q = i - 6144;
            int tmk = q >> 9, lane = (q >> 3) & 63, j = q & 7;
            int kt = tmk & 1, tm = tmk >> 1;
            int t = tm / 3, m = tm - t * 3;
            int k = kt * 32 + (lane >> 4) * 8 + j, ch = m * 16 + (lane & 15);
            int l = ch >> 4, o = ch & 15;
            float s = 0.f;
#pragma unroll
            for (int c = 0; c < 8; ++c)
                s += s_ai[t * 8 + c] * fw3[k * 384 + l * 128 + c * 16 + o];
            w3ta[q] = (__bf16)s;
        } else {
            int q2 = i - 36864;
            int t = q2 / 48, ch = q2 - t * 48;
            int l = ch >> 4, o = ch & 15;
            float s = 0.f;
#pragma unroll
            for (int c = 0; c < 8; ++c)
                s += s_ai[t * 8 + c] * fb3[l * 128 + c * 16 + o];
            b3t[q2] = s;
        }
    }
}

// ---------- count: per-dst rank + per-type rank (type packed into high bits) ----------
__global__ void count_k(const int* __restrict__ esrc, const int* __restrict__ edst,
                        const int* __restrict__ A,
                        int* __restrict__ cnt_dst, int* __restrict__ cnt_t,
                        int* __restrict__ rdst, int* __restrict__ rtp) {
    __shared__ int lcnt[10];
    __shared__ int gbase[10];
    int tid = threadIdx.x;
    if (tid < 10) lcnt[tid] = 0;
    __syncthreads();
    int e = blockIdx.x * blockDim.x + tid;
    int t = 0, lr = 0;
    bool valid = e < NE;
    if (valid) {
        rdst[e] = atomicAdd(&cnt_dst[edst[e]], 1);
        t = A[esrc[e]];
        lr = atomicAdd(&lcnt[t], 1);
    }
    __syncthreads();
    if (tid < 10) gbase[tid] = atomicAdd(&cnt_t[tid], lcnt[tid]);
    __syncthreads();
    if (valid) rtp[e] = (t << 20) | (gbase[t] + lr);
}

// ---------- single-block scan: off_dst + 64-padded type offsets ----------
__global__ __launch_bounds__(1024) void scan_k(const int* __restrict__ cnt_dst,
                                               int* __restrict__ off_dst,
                                               const int* __restrict__ cnt_t,
                                               int* __restrict__ offt_pad) {
    __shared__ int s_part[1024];
    const int tid = threadIdx.x;
    const int CH = 25;
    int base = tid * CH;
    int sum = 0;
    for (int i = 0; i < CH; ++i) {
        int idx = base + i;
        sum += (idx < NN) ? cnt_dst[idx] : 0;
    }
    s_part[tid] = sum;
    __syncthreads();
    for (int off = 1; off < 1024; off <<= 1) {
        int v = (tid >= off) ? s_part[tid - off] : 0;
        __syncthreads();
        s_part[tid] += v;
        __syncthreads();
    }
    int run = s_part[tid] - sum;
    for (int i = 0; i < CH; ++i) {
        int idx = base + i;
        if (idx < NN) {
            off_dst[idx] = run;
            run += cnt_dst[idx];
        }
    }
    if (tid == 1023) off_dst[NN] = s_part[1023];
    if (tid == 0) {
        int running = 0;
        for (int t = 0; t < 10; ++t) {
            offt_pad[t] = running;
            int c = cnt_t[t];
            running += ((c + 63) >> 6) << 6;
        }
        offt_pad[10] = running;
    }
}

// ---------- scatter: CSR slot per edge + type-bucketed (64-padded) edge list ----------
__global__ void scatter_k(const int* __restrict__ edst,
                          const int* __restrict__ off_dst, const int* __restrict__ offt_pad,
                          const int* __restrict__ rdst, const int* __restrict__ rtp,
                          int* __restrict__ slotarr, int* __restrict__ tlist) {
    int e = blockIdx.x * blockDim.x + threadIdx.x;
    if (e >= NE) return;
    slotarr[e] = off_dst[edst[e]] + rdst[e];
    int rp = rtp[e];
    tlist[offt_pad[rp >> 20] + (rp & 0xFFFFF)] = e;
}

// ---------- edge kernel: 1 wave = 64 edges; 3 MFMA GEMMs; payload in CSR order ----------
__global__ __launch_bounds__(64) void edge_k(
    const int* __restrict__ tlist, const int* __restrict__ A,
    const int* __restrict__ esrc, const int* __restrict__ edst,
    const float* __restrict__ pos, const float* __restrict__ shifts,
    const float* __restrict__ cell, const int* __restrict__ batch,
    const int* __restrict__ slotarr,
    const __bf16* __restrict__ w1a, const __bf16* __restrict__ w2a,
    const __bf16* __restrict__ w3ta,
    const float* __restrict__ fb2, const float* __restrict__ b3t,
    float* __restrict__ payload) {
    __shared__ __bf16 embuf[64 * 40];   // rows 80B: [8 gauss][1.0][zeros..31][pad]
    __shared__ __bf16 h1buf[64 * 72];   // rows 144B (64 bf16 + 8 pad)
    __shared__ __bf16 h2buf[64 * 72];
    __shared__ int slotbuf[64];
    const int lane = threadIdx.x;
    const int base = blockIdx.x * 64;
    const int e0 = tlist[base];
    if (e0 < 0) return;  // fully padded trailing block (uniform)
    int t_blk = __builtin_amdgcn_readfirstlane(A[esrc[e0]]);

    int eid = tlist[base + lane];
    const bool valid = eid >= 0;
    if (!valid) eid = e0;  // pad lanes duplicate a real edge (never stored)

    // ---- geometry ----
    const int src = esrc[eid], dstn = edst[eid];
    const int b = batch[src];
    const float* cb = cell + b * 9;
    const float sh0 = shifts[eid * 3 + 0], sh1 = shifts[eid * 3 + 1], sh2 = shifts[eid * 3 + 2];
    float vx = pos[dstn * 3 + 0] - pos[src * 3 + 0] + sh0 * cb[0] + sh1 * cb[3] + sh2 * cb[6];
    float vy = pos[dstn * 3 + 1] - pos[src * 3 + 1] + sh0 * cb[1] + sh1 * cb[4] + sh2 * cb[7];
    float vz = pos[dstn * 3 + 2] - pos[src * 3 + 2] + sh0 * cb[2] + sh1 * cb[5] + sh2 * cb[8];
    const float len = sqrtf(vx * vx + vy * vy + vz * vz + 1e-12f);
    const float il = 1.0f / len;

    const int slot_e = valid ? slotarr[eid] : -1;
    slotbuf[lane] = slot_e;
    if (valid) {
        float* pu = payload + (size_t)slot_e * PLS;
        pu[48] = vx * il; pu[49] = vy * il; pu[50] = vz * il;
    }

    // ---- radial basis row (K padded to 32; k=8 -> 1.0 for bias folding) ----
    bf16x8 er0;
#pragma unroll
    for (int k = 0; k < 8; ++k) {
        float d = (len - (5.0f * (float)(k + 1) / 9.0f)) * 1.8f;
        er0[k] = (__bf16)(__expf(-d * d) * 2.525381361380528f);  // sqrt(8)/1.12
    }
    bf16x8 er1 = {};
    er1[0] = (__bf16)1.0f;
    bf16x8 zz = {};
    *(bf16x8*)&embuf[lane * 40 + 0]  = er0;
    *(bf16x8*)&embuf[lane * 40 + 8]  = er1;
    *(bf16x8*)&embuf[lane * 40 + 16] = zz;
    *(bf16x8*)&embuf[lane * 40 + 24] = zz;

    // ---- A-fragments (weights, transposed layout) + biases ----
    bf16x8 a1[4], a2[8], a3[6];
#pragma unroll
    for (int m = 0; m < 4; ++m) a1[m] = *(const bf16x8*)(w1a + (m * 64 + lane) * 8);
#pragma unroll
    for (int i = 0; i < 8; ++i) a2[i] = *(const bf16x8*)(w2a + (i * 64 + lane) * 8);
#pragma unroll
    for (int i = 0; i < 6; ++i)
        a3[i] = *(const bf16x8*)(w3ta + ((size_t)(t_blk * 6 + i) * 64 + lane) * 8);
    const int qr = (lane >> 4) * 4;
    const int q8 = (lane >> 4) * 8;
    f32x4 bias2[4], bias3[3];
#pragma unroll
    for (int m = 0; m < 4; ++m) bias2[m] = *(const f32x4*)(fb2 + m * 16 + qr);
#pragma unroll
    for (int m = 0; m < 3; ++m) bias3[m] = *(const f32x4*)(b3t + t_blk * 48 + m * 16 + qr);
    __syncthreads();

    const float SC = (float)NN / (float)NE;  // 1/16
    const int colrow = lane & 15;
#pragma unroll 1
    for (int n = 0; n < 4; ++n) {
        const int erow = n * 16 + colrow;
        // GEMM1: h1 = silu(emb @ W1 + b1)   (bias via constant-1 channel)
        bf16x8 b1 = *(bf16x8*)&embuf[erow * 40 + q8];
#pragma unroll
        for (int m = 0; m < 4; ++m) {
            f32x4 c = {0.f, 0.f, 0.f, 0.f};
            c = __builtin_amdgcn_mfma_f32_16x16x32_bf16(a1[m], b1, c, 0, 0, 0);
            bf16x4 hp;
#pragma unroll
            for (int r = 0; r < 4; ++r) hp[r] = (__bf16)silu_f(c[r]);
            *(bf16x4*)&h1buf[erow * 72 + m * 16 + qr] = hp;
        }
        __syncthreads();
        // GEMM2: h2 = silu(h1 @ W2 + b2)
        bf16x8 b20 = *(bf16x8*)&h1buf[erow * 72 + q8];
        bf16x8 b21 = *(bf16x8*)&h1buf[erow * 72 + 32 + q8];
#pragma unroll
        for (int m = 0; m < 4; ++m) {
            f32x4 c = bias2[m];
            c = __builtin_amdgcn_mfma_f32_16x16x32_bf16(a2[m * 2 + 0], b20, c, 0, 0, 0);
            c = __builtin_amdgcn_mfma_f32_16x16x32_bf16(a2[m * 2 + 1], b21, c, 0, 0, 0);
            bf16x4 hp;
#pragma unroll
            for (int r = 0; r < 4; ++r) hp[r] = (__bf16)silu_f(c[r]);
            *(bf16x4*)&h2buf[erow * 72 + m * 16 + qr] = hp;
        }
        __syncthreads();
        // GEMM3: s = (h2 @ W3t + b3t) * SC  -> payload CSR row
        bf16x8 b30 = *(bf16x8*)&h2buf[erow * 72 + q8];
        bf16x8 b31 = *(bf16x8*)&h2buf[erow * 72 + 32 + q8];
        const int slot_c = slotbuf[erow];
#pragma unroll
        for (int m = 0; m < 3; ++m) {
            f32x4 c = bias3[m];
            c = __builtin_amdgcn_mfma_f32_16x16x32_bf16(a3[m * 2 + 0], b30, c, 0, 0, 0);
            c = __builtin_amdgcn_mfma_f32_16x16x32_bf16(a3[m * 2 + 1], b31, c, 0, 0, 0);
            if (slot_c >= 0) {
                float* pr = payload + (size_t)slot_c * PLS + m * 16 + qr;
                pr[0] = c[0] * SC; pr[1] = c[1] * SC;
                pr[2] = c[2] * SC; pr[3] = c[3] * SC;
            }
        }
        __syncthreads();
    }
}

// ---------- gather: contiguous CSR payload rows -> expand outer products -> out ----------
__global__ __launch_bounds__(GB) void gather_k(const int* __restrict__ off_dst,
                                               const float* __restrict__ payload,
                                               float* __restrict__ out) {
    __shared__ float sp[8][52];
    const int n = blockIdx.x;
    const int tid = threadIdx.x;
    const int lo = off_dst[n], hi = off_dst[n + 1];
    int kind = 3, c = 0, ui = 0, uj = 0;
    if (tid < 16) { kind = 0; c = tid; }
    else if (tid < 64) { int q = tid - 16; kind = 1; c = q / 3; ui = q % 3; }
    else if (tid < 208) { int q = tid - 64; kind = 2; c = q / 9; int ij = q % 9; ui = ij / 3; uj = ij % 3; }
    float acc = 0.f;
    for (int p0 = lo; p0 < hi; p0 += 8) {
        int m = min(8, hi - p0);
        int cnt = m * 52;
        for (int idx = tid; idx < cnt; idx += GB)
            ((float*)sp)[idx] = payload[(size_t)p0 * PLS + idx];
        __syncthreads();
        for (int r = 0; r < m; ++r) {
            if (kind == 0) acc += sp[r][c];
            else if (kind == 1) acc += sp[r][16 + c] * sp[r][48 + ui];
            else if (kind == 2) acc += sp[r][32 + c] * sp[r][48 + ui] * sp[r][48 + uj];
        }
        __syncthreads();
    }
    if (tid < 208) {
        out[(size_t)n * TD + tid] = acc;
        out[(size_t)n * TD + 208 + tid] = 0.f;
    }
}

extern "C" void kernel_launch(void* const* d_in, const int* in_sizes, int n_in,
                              void* d_out, int out_size, void* d_ws, size_t ws_size,
                              hipStream_t stream) {
    const float* pos       = (const float*)d_in[0];
    const int*   A         = (const int*)d_in[1];
    const int*   batch     = (const int*)d_in[2];
    const int*   esrc      = (const int*)d_in[3];
    const int*   edst      = (const int*)d_in[4];
    const float* shifts    = (const float*)d_in[5];
    const float* cell      = (const float*)d_in[6];
    const float* emb_table = (const float*)d_in[7];
    const float* aw1       = (const float*)d_in[8];
    const float* ab1       = (const float*)d_in[9];
    const float* aw2       = (const float*)d_in[10];
    const float* ab2       = (const float*)d_in[11];
    const float* fw1       = (const float*)d_in[12];
    const float* fb1       = (const float*)d_in[13];
    const float* fw2       = (const float*)d_in[14];
    const float* fb2       = (const float*)d_in[15];
    const float* fw3       = (const float*)d_in[16];
    const float* fb3       = (const float*)d_in[17];
    float* out = (float*)d_out;

    // ---- ws layout (bytes from base) ----
    char* base = (char*)d_ws;
    __bf16* w1a    = (__bf16*)(base + 0);        // 4096 B
    __bf16* w2a    = (__bf16*)(base + 4096);     // 8192 B
    __bf16* w3ta   = (__bf16*)(base + 12288);    // 61440 B
    float*  b3t    = (float*)(base + 73728);     // 1920 B
    int* cnt_dst   = (int*)(base + 75648);       // 25008*4
    int* cnt_t     = (int*)(base + 175680);      // 64 B
    int* off_dst   = (int*)(base + 175744);      // 25008*4
    int* offt_pad  = (int*)(base + 275776);      // 64 B
    int* rdst      = (int*)(base + 275840);      // 1.6 MB
    int* rtp       = (int*)(base + 1875840);     // 1.6 MB
    int* slotarr   = (int*)(base + 3475840);     // 1.6 MB
    int* tlist     = (int*)(base + 5075840);     // 400640*4
    float* payload = (float*)(base + 6678400);   // 400000*52*4 = 83.2 MB

    hipMemsetAsync(tlist, 0xFF, NT_LIST * 4, stream);
    hipMemsetAsync(cnt_dst, 0, (25008 + 16) * 4, stream);
    wsprep<<<64, 256, 0, stream>>>(emb_table, aw1, ab1, aw2, ab2,
                                   fw1, fb1, fw2, fw3, fb3, w1a, w2a, w3ta, b3t);
    count_k<<<(NE + 255) / 256, 256, 0, stream>>>(esrc, edst, A, cnt_dst, cnt_t, rdst, rtp);
    scan_k<<<1, 1024, 0, stream>>>(cnt_dst, off_dst, cnt_t, offt_pad);
    scatter_k<<<(NE + 255) / 256, 256, 0, stream>>>(edst, off_dst, offt_pad,
                                                    rdst, rtp, slotarr, tlist);
    edge_k<<<NBLK64, 64, 0, stream>>>(tlist, A, esrc, edst, pos, shifts, cell, batch,
                                      slotarr, w1a, w2a, w3ta, fb2, b3t, payload);
    gather_k<<<NN, GB, 0, stream>>>(off_dst, payload, out);
}

// Round 4
// 245.043 us; speedup vs baseline: 19.0043x; 1.2652x over previous
//
#include <hip/hip_runtime.h>
#include <math.h>

#define NN 25000
#define NE 400000
#define TD 416
#define NBLK64 6260            // covers 400000 + 10*63 padded slots
#define NT_LIST (NBLK64 * 64)  // 400640
#define PLH 56                 // payload row stride in halves (112 B)
#define GROWS 32

typedef __attribute__((ext_vector_type(8))) __bf16 bf16x8;
typedef __attribute__((ext_vector_type(4))) _Float16 f16x4;
typedef __attribute__((ext_vector_type(4))) float f32x4;

__device__ __forceinline__ float silu_f(float x) {
    return x * (1.0f / (1.0f + __expf(-x)));
}

// ---------- fused: [blocks 0..63] weight prep, [blocks 64..] count ----------
__global__ __launch_bounds__(256) void prep_count_k(
    const float* __restrict__ emb_table,
    const float* __restrict__ aw1, const float* __restrict__ ab1,
    const float* __restrict__ aw2, const float* __restrict__ ab2,
    const float* __restrict__ fw1, const float* __restrict__ fb1,
    const float* __restrict__ fw2,
    const float* __restrict__ fw3, const float* __restrict__ fb3,
    __bf16* __restrict__ w1a, __bf16* __restrict__ w2a,
    __bf16* __restrict__ w3ta, float* __restrict__ b3t,
    const int* __restrict__ esrc, const int* __restrict__ edst,
    const int* __restrict__ A,
    int* __restrict__ cnt_dst, int* __restrict__ cnt_t,
    int* __restrict__ rdst, int* __restrict__ rtp) {
    const int tid = threadIdx.x;
    if (blockIdx.x < 64) {
        // ---------------- weight prep ----------------
        __shared__ float s_ai[80];
        if (tid < 10) {
            float acc[8];
#pragma unroll
            for (int o = 0; o < 8; ++o) acc[o] = ab2[o];
            for (int j = 0; j < 64; ++j) {
                float h = ab1[j];
#pragma unroll
                for (int i = 0; i < 16; ++i) h += emb_table[tid * 16 + i] * aw1[i * 64 + j];
                h = silu_f(h);
#pragma unroll
                for (int o = 0; o < 8; ++o) acc[o] += h * aw2[j * 8 + o];
            }
#pragma unroll
            for (int o = 0; o < 8; ++o) s_ai[tid * 8 + o] = acc[o];
        }
        __syncthreads();
        for (int i = blockIdx.x * 256 + tid; i < 37344; i += 64 * 256) {
            if (i < 2048) {
                int m = i >> 9, r = i & 511, lane = r >> 3, j = r & 7;
                int k = (lane >> 4) * 8 + j, ch = m * 16 + (lane & 15);
                float v = (k < 8) ? fw1[k * 64 + ch] : ((k == 8) ? fb1[ch] : 0.0f);
                w1a[i] = (__bf16)v;
            } else if (i < 6144) {
                int q = i - 2048;
                int mk = q >> 9, lane = (q >> 3) & 63, j = q & 7;
                int m = mk >> 1, kt = mk & 1;
                int k = kt * 32 + (lane >> 4) * 8 + j, ch = m * 16 + (lane & 15);
                w2a[q] = (__bf16)fw2[k * 64 + ch];
            } else if (i < 36864) {
                int q = i - 6144;
                int tmk = q >> 9, lane = (q >> 3) & 63, j = q & 7;
                int kt = tmk & 1, tm = tmk >> 1;
                int t = tm / 3, m = tm - t * 3;
                int k = kt * 32 + (lane >> 4) * 8 + j, ch = m * 16 + (lane & 15);
                int l = ch >> 4, o = ch & 15;
                float s = 0.f;
#pragma unroll
                for (int c = 0; c < 8; ++c)
                    s += s_ai[t * 8 + c] * fw3[k * 384 + l * 128 + c * 16 + o];
                w3ta[q] = (__bf16)s;
            } else {
                int q2 = i - 36864;
                int t = q2 / 48, ch = q2 - t * 48;
                int l = ch >> 4, o = ch & 15;
                float s = 0.f;
#pragma unroll
                for (int c = 0; c < 8; ++c)
                    s += s_ai[t * 8 + c] * fb3[l * 128 + c * 16 + o];
                b3t[q2] = s;
            }
        }
    } else {
        // ---------------- count: per-dst rank + per-type rank ----------------
        __shared__ int lcnt[10];
        __shared__ int gbase[10];
        if (tid < 10) lcnt[tid] = 0;
        __syncthreads();
        int e = (blockIdx.x - 64) * 256 + tid;
        int t = 0, lr = 0;
        bool valid = e < NE;
        if (valid) {
            rdst[e] = atomicAdd(&cnt_dst[edst[e]], 1);
            t = A[esrc[e]];
            lr = atomicAdd(&lcnt[t], 1);
        }
        __syncthreads();
        if (tid < 10) gbase[tid] = atomicAdd(&cnt_t[tid], lcnt[tid]);
        __syncthreads();
        if (valid) rtp[e] = (t << 20) | (gbase[t] + lr);
    }
}

// ---------- single-block scan: off_dst + padded type offsets + tlist pad fill ----------
__global__ __launch_bounds__(1024) void scan_k(const int* __restrict__ cnt_dst,
                                               int* __restrict__ off_dst,
                                               const int* __restrict__ cnt_t,
                                               int* __restrict__ offt_pad,
                                               int* __restrict__ tlist) {
    __shared__ int s_part[1024];
    __shared__ int s_offt[11];
    __shared__ int s_cnt[10];
    const int tid = threadIdx.x;
    const int CH = 25;
    int base = tid * CH;
    int sum = 0;
    for (int i = 0; i < CH; ++i) {
        int idx = base + i;
        sum += (idx < NN) ? cnt_dst[idx] : 0;
    }
    s_part[tid] = sum;
    __syncthreads();
    for (int off = 1; off < 1024; off <<= 1) {
        int v = (tid >= off) ? s_part[tid - off] : 0;
        __syncthreads();
        s_part[tid] += v;
        __syncthreads();
    }
    int run = s_part[tid] - sum;
    for (int i = 0; i < CH; ++i) {
        int idx = base + i;
        if (idx < NN) {
            off_dst[idx] = run;
            run += cnt_dst[idx];
        }
    }
    if (tid == 1023) off_dst[NN] = s_part[1023];
    if (tid == 0) {
        int running = 0;
        for (int t = 0; t < 10; ++t) {
            s_offt[t] = running;
            offt_pad[t] = running;
            int c = cnt_t[t];
            s_cnt[t] = c;
            running += ((c + 63) >> 6) << 6;
        }
        s_offt[10] = running;
        offt_pad[10] = running;
    }
    __syncthreads();
    // fill only the pad slots with -1 (replaces the 1.6 MB memset)
    for (int t = 0; t < 10; ++t)
        for (int i = s_offt[t] + s_cnt[t] + tid; i < s_offt[t + 1]; i += 1024)
            tlist[i] = -1;
    for (int i = s_offt[10] + tid; i < NT_LIST; i += 1024) tlist[i] = -1;
}

// ---------- scatter: CSR slot per edge + type-bucketed (64-padded) edge list ----------
__global__ void scatter_k(const int* __restrict__ edst,
                          const int* __restrict__ off_dst, const int* __restrict__ offt_pad,
                          const int* __restrict__ rdst, const int* __restrict__ rtp,
                          int* __restrict__ slotarr, int* __restrict__ tlist) {
    int e = blockIdx.x * blockDim.x + threadIdx.x;
    if (e >= NE) return;
    slotarr[e] = off_dst[edst[e]] + rdst[e];
    int rp = rtp[e];
    tlist[offt_pad[rp >> 20] + (rp & 0xFFFFF)] = e;
}

// ---------- edge kernel: 1 wave = 64 edges; 3 MFMA GEMMs; fp16 payload, CSR order ----------
__global__ __launch_bounds__(64) void edge_k(
    const int* __restrict__ tlist, const int* __restrict__ A,
    const int* __restrict__ esrc, const int* __restrict__ edst,
    const float* __restrict__ pos, const float* __restrict__ shifts,
    const float* __restrict__ cell, const int* __restrict__ batch,
    const int* __restrict__ slotarr,
    const __bf16* __restrict__ w1a, const __bf16* __restrict__ w2a,
    const __bf16* __restrict__ w3ta,
    const float* __restrict__ fb2, const float* __restrict__ b3t,
    _Float16* __restrict__ payload) {
    __shared__ __bf16 embuf[64 * 36];  // 4.6 KB, row stride 36 halves
    __shared__ __bf16 h1buf[16 * 72];  // 2.3 KB (only current 16 edge-rows live)
    __shared__ __bf16 h2buf[16 * 72];  // 2.3 KB
    __shared__ int slotbuf[64];
    const int lane = threadIdx.x;
    const int base = blockIdx.x * 64;
    const int e0 = tlist[base];
    if (e0 < 0) return;  // fully padded trailing block (uniform exit)
    int t_blk = __builtin_amdgcn_readfirstlane(A[esrc[e0]]);

    int eid = tlist[base + lane];
    const bool valid = eid >= 0;
    if (!valid) eid = e0;  // pad lanes duplicate a real edge (never stored)

    // ---- geometry ----
    const int src = esrc[eid], dstn = edst[eid];
    const int b = batch[src];
    const float* cb = cell + b * 9;
    const float sh0 = shifts[eid * 3 + 0], sh1 = shifts[eid * 3 + 1], sh2 = shifts[eid * 3 + 2];
    float vx = pos[dstn * 3 + 0] - pos[src * 3 + 0] + sh0 * cb[0] + sh1 * cb[3] + sh2 * cb[6];
    float vy = pos[dstn * 3 + 1] - pos[src * 3 + 1] + sh0 * cb[1] + sh1 * cb[4] + sh2 * cb[7];
    float vz = pos[dstn * 3 + 2] - pos[src * 3 + 2] + sh0 * cb[2] + sh1 * cb[5] + sh2 * cb[8];
    const float len = sqrtf(vx * vx + vy * vy + vz * vz + 1e-12f);
    const float il = 1.0f / len;

    const int slot_e = valid ? slotarr[eid] : -1;
    slotbuf[lane] = slot_e;
    if (valid) {
        float* pu = (float*)(payload + (size_t)slot_e * PLH + 48);
        pu[0] = vx * il; pu[1] = vy * il; pu[2] = vz * il;
    }

    // ---- radial basis row (K=32; k=8 -> 1.0 folds bias) ----
    bf16x8 er0;
#pragma unroll
    for (int k = 0; k < 8; ++k) {
        float d = (len - (5.0f * (float)(k + 1) / 9.0f)) * 1.8f;
        er0[k] = (__bf16)(__expf(-d * d) * 2.525381361380528f);  // sqrt(8)/1.12
    }
    bf16x8 er1 = {};
    er1[0] = (__bf16)1.0f;
    bf16x8 zz = {};
    *(bf16x8*)&embuf[lane * 36 + 0]  = er0;
    *(bf16x8*)&embuf[lane * 36 + 8]  = er1;
    *(bf16x8*)&embuf[lane * 36 + 16] = zz;
    *(bf16x8*)&embuf[lane * 36 + 24] = zz;

    // ---- A-fragments (weights) + biases ----
    bf16x8 a1[4], a2[8], a3[6];
#pragma unroll
    for (int m = 0; m < 4; ++m) a1[m] = *(const bf16x8*)(w1a + (m * 64 + lane) * 8);
#pragma unroll
    for (int i = 0; i < 8; ++i) a2[i] = *(const bf16x8*)(w2a + (i * 64 + lane) * 8);
#pragma unroll
    for (int i = 0; i < 6; ++i)
        a3[i] = *(const bf16x8*)(w3ta + ((size_t)(t_blk * 6 + i) * 64 + lane) * 8);
    const int qr = (lane >> 4) * 4;
    const int q8 = (lane >> 4) * 8;
    f32x4 bias2[4], bias3[3];
#pragma unroll
    for (int m = 0; m < 4; ++m) bias2[m] = *(const f32x4*)(fb2 + m * 16 + qr);
#pragma unroll
    for (int m = 0; m < 3; ++m) bias3[m] = *(const f32x4*)(b3t + t_blk * 48 + m * 16 + qr);
    __syncthreads();

    const float SC = (float)NN / (float)NE;  // 1/16
    const int colrow = lane & 15;
#pragma unroll 1
    for (int n = 0; n < 4; ++n) {
        const int erow = n * 16 + colrow;
        // GEMM1: h1 = silu(emb @ W1 + b1)
        bf16x8 b1 = *(bf16x8*)&embuf[erow * 36 + q8];
#pragma unroll
        for (int m = 0; m < 4; ++m) {
            f32x4 c = {0.f, 0.f, 0.f, 0.f};
            c = __builtin_amdgcn_mfma_f32_16x16x32_bf16(a1[m], b1, c, 0, 0, 0);
            __bf16 hp[4];
#pragma unroll
            for (int r = 0; r < 4; ++r) hp[r] = (__bf16)silu_f(c[r]);
            *(uint2*)&h1buf[colrow * 72 + m * 16 + qr] = *(uint2*)hp;
        }
        __syncthreads();
        // GEMM2: h2 = silu(h1 @ W2 + b2)
        bf16x8 b20 = *(bf16x8*)&h1buf[colrow * 72 + q8];
        bf16x8 b21 = *(bf16x8*)&h1buf[colrow * 72 + 32 + q8];
#pragma unroll
        for (int m = 0; m < 4; ++m) {
            f32x4 c = bias2[m];
            c = __builtin_amdgcn_mfma_f32_16x16x32_bf16(a2[m * 2 + 0], b20, c, 0, 0, 0);
            c = __builtin_amdgcn_mfma_f32_16x16x32_bf16(a2[m * 2 + 1], b21, c, 0, 0, 0);
            __bf16 hp[4];
#pragma unroll
            for (int r = 0; r < 4; ++r) hp[r] = (__bf16)silu_f(c[r]);
            *(uint2*)&h2buf[colrow * 72 + m * 16 + qr] = *(uint2*)hp;
        }
        __syncthreads();
        // GEMM3: s = (h2 @ W3t + b3t) * SC -> fp16 payload row (CSR slot)
        bf16x8 b30 = *(bf16x8*)&h2buf[colrow * 72 + q8];
        bf16x8 b31 = *(bf16x8*)&h2buf[colrow * 72 + 32 + q8];
        const int slot_c = slotbuf[erow];
#pragma unroll
        for (int m = 0; m < 3; ++m) {
            f32x4 c = bias3[m];
            c = __builtin_amdgcn_mfma_f32_16x16x32_bf16(a3[m * 2 + 0], b30, c, 0, 0, 0);
            c = __builtin_amdgcn_mfma_f32_16x16x32_bf16(a3[m * 2 + 1], b31, c, 0, 0, 0);
            if (slot_c >= 0) {
                f16x4 hp;
#pragma unroll
                for (int r = 0; r < 4; ++r) hp[r] = (_Float16)(c[r] * SC);
                *(f16x4*)(payload + (size_t)slot_c * PLH + m * 16 + qr) = hp;
            }
        }
        __syncthreads();
    }
}

// ---------- gather: contiguous fp16 CSR rows -> factor-table expansion -> out ----------
__global__ __launch_bounds__(256) void gather_k(const int* __restrict__ off_dst,
                                                const _Float16* __restrict__ payload,
                                                float* __restrict__ out) {
    __shared__ __align__(16) _Float16 sp_s[GROWS][PLH];  // 3.5 KB
    __shared__ float sfac[GROWS][16];                    // 2 KB
    const int n = blockIdx.x;
    const int tid = threadIdx.x;
    const int lo = off_dst[n], hi = off_dst[n + 1];
    // per-thread index table (computed once; uniform inner loop, no divergence)
    int voff = 0, foff = 0;
    if (tid < 16) { voff = tid; foff = 0; }
    else if (tid < 64) { int q = tid - 16; voff = 16 + q / 3; foff = 1 + q % 3; }
    else if (tid < 208) { int q = tid - 64; voff = 32 + q / 9; foff = 4 + q % 9; }
    float acc = 0.f;
    for (int p0 = lo; p0 < hi; p0 += GROWS) {
        const int m = min(GROWS, hi - p0);
        // stage m rows (7 x uint4 each)
        if (tid < m * 8) {
            int r = tid >> 3, q = tid & 7;
            if (q < 7)
                ((uint4*)&sp_s[r][0])[q] = ((const uint4*)(payload + (size_t)(p0 + r) * PLH))[q];
        }
        __syncthreads();
        // build factor table: {1, ux,uy,uz, uu[9]}
        for (int idx = tid; idx < m * 16; idx += 256) {
            int r = idx >> 4, f = idx & 15;
            if (f < 13) {
                const float* uf = (const float*)&sp_s[r][48];
                float v;
                if (f == 0) v = 1.0f;
                else if (f < 4) v = uf[f - 1];
                else { int g = f - 4; v = uf[g / 3] * uf[g % 3]; }
                sfac[r][f] = v;
            }
        }
        __syncthreads();
        if (tid < 208)
            for (int r = 0; r < m; ++r)
                acc += (float)sp_s[r][voff] * sfac[r][foff];
        __syncthreads();
    }
    if (tid < 208) {
        out[(size_t)n * TD + tid] = acc;
        out[(size_t)n * TD + 208 + tid] = 0.f;
    }
}

extern "C" void kernel_launch(void* const* d_in, const int* in_sizes, int n_in,
                              void* d_out, int out_size, void* d_ws, size_t ws_size,
                              hipStream_t stream) {
    const float* pos       = (const float*)d_in[0];
    const int*   A         = (const int*)d_in[1];
    const int*   batch     = (const int*)d_in[2];
    const int*   esrc      = (const int*)d_in[3];
    const int*   edst      = (const int*)d_in[4];
    const float* shifts    = (const float*)d_in[5];
    const float* cell      = (const float*)d_in[6];
    const float* emb_table = (const float*)d_in[7];
    const float* aw1       = (const float*)d_in[8];
    const float* ab1       = (const float*)d_in[9];
    const float* aw2       = (const float*)d_in[10];
    const float* ab2       = (const float*)d_in[11];
    const float* fw1       = (const float*)d_in[12];
    const float* fb1       = (const float*)d_in[13];
    const float* fw2       = (const float*)d_in[14];
    const float* fb2       = (const float*)d_in[15];
    const float* fw3       = (const float*)d_in[16];
    const float* fb3       = (const float*)d_in[17];
    float* out = (float*)d_out;

    // ---- ws layout (bytes from base) ----
    char* base = (char*)d_ws;
    __bf16* w1a    = (__bf16*)(base + 0);        // 4096 B
    __bf16* w2a    = (__bf16*)(base + 4096);     // 8192 B
    __bf16* w3ta   = (__bf16*)(base + 12288);    // 61440 B
    float*  b3t    = (float*)(base + 73728);     // 1920 B
    int* cnt_dst   = (int*)(base + 75648);       // 25008*4
    int* cnt_t     = (int*)(base + 175680);      // 64 B   (memset together w/ cnt_dst)
    int* off_dst   = (int*)(base + 175744);      // 25008*4
    int* offt_pad  = (int*)(base + 275776);      // 64 B
    int* rdst      = (int*)(base + 275840);      // 1.6 MB
    int* rtp       = (int*)(base + 1875840);     // 1.6 MB
    int* slotarr   = (int*)(base + 3475840);     // 1.6 MB
    int* tlist     = (int*)(base + 5075840);     // 400640*4
    _Float16* payload = (_Float16*)(base + 6678400);  // 400000*56*2 = 44.8 MB

    hipMemsetAsync(cnt_dst, 0, 100096, stream);  // cnt_dst + cnt_t
    prep_count_k<<<64 + (NE + 255) / 256, 256, 0, stream>>>(
        emb_table, aw1, ab1, aw2, ab2, fw1, fb1, fw2, fw3, fb3,
        w1a, w2a, w3ta, b3t, esrc, edst, A, cnt_dst, cnt_t, rdst, rtp);
    scan_k<<<1, 1024, 0, stream>>>(cnt_dst, off_dst, cnt_t, offt_pad, tlist);
    scatter_k<<<(NE + 255) / 256, 256, 0, stream>>>(edst, off_dst, offt_pad,
                                                    rdst, rtp, slotarr, tlist);
    edge_k<<<NBLK64, 64, 0, stream>>>(tlist, A, esrc, edst, pos, shifts, cell, batch,
                                      slotarr, w1a, w2a, w3ta, fb2, b3t, payload);
    gather_k<<<NN, 256, 0, stream>>>(off_dst, payload, out);
}

// Round 5
// 220.517 us; speedup vs baseline: 21.1179x; 1.1112x over previous
//
#include <hip/hip_runtime.h>
#include <math.h>

#define NN 25000
#define NE 400000
#define TD 416
#define TCAP 46080             // per-type tlist/payload capacity (64-aligned, mean 40000 + 7.8 sigma)
#define NROWS (TCAP * 10)      // 460800 payload rows
#define PLH 64                 // payload row stride in halves (128 B = 2 lines)
#define GROWS 32

typedef __attribute__((ext_vector_type(8))) __bf16 bf16x8;
typedef __attribute__((ext_vector_type(4))) _Float16 f16x4;
typedef __attribute__((ext_vector_type(4))) float f32x4;

__device__ __forceinline__ float silu_f(float x) {
    return x * (1.0f / (1.0f + __expf(-x)));
}

// ---------- fused: [blocks 0..63] weight prep, [blocks 64..] count ----------
__global__ __launch_bounds__(256) void prep_count_k(
    const float* __restrict__ emb_table,
    const float* __restrict__ aw1, const float* __restrict__ ab1,
    const float* __restrict__ aw2, const float* __restrict__ ab2,
    const float* __restrict__ fw1, const float* __restrict__ fb1,
    const float* __restrict__ fw2,
    const float* __restrict__ fw3, const float* __restrict__ fb3,
    __bf16* __restrict__ w1a, __bf16* __restrict__ w2a,
    __bf16* __restrict__ w3ta, float* __restrict__ b3t,
    const int* __restrict__ esrc, const int* __restrict__ edst,
    const int* __restrict__ A,
    int* __restrict__ cnt_dst, int* __restrict__ cnt_t,
    int* __restrict__ rdst, int* __restrict__ rtp) {
    const int tid = threadIdx.x;
    if (blockIdx.x < 64) {
        __shared__ float s_ai[80];
        if (tid < 10) {
            float acc[8];
#pragma unroll
            for (int o = 0; o < 8; ++o) acc[o] = ab2[o];
            for (int j = 0; j < 64; ++j) {
                float h = ab1[j];
#pragma unroll
                for (int i = 0; i < 16; ++i) h += emb_table[tid * 16 + i] * aw1[i * 64 + j];
                h = silu_f(h);
#pragma unroll
                for (int o = 0; o < 8; ++o) acc[o] += h * aw2[j * 8 + o];
            }
#pragma unroll
            for (int o = 0; o < 8; ++o) s_ai[tid * 8 + o] = acc[o];
        }
        __syncthreads();
        for (int i = blockIdx.x * 256 + tid; i < 37344; i += 64 * 256) {
            if (i < 2048) {
                int m = i >> 9, r = i & 511, lane = r >> 3, j = r & 7;
                int k = (lane >> 4) * 8 + j, ch = m * 16 + (lane & 15);
                float v = (k < 8) ? fw1[k * 64 + ch] : ((k == 8) ? fb1[ch] : 0.0f);
                w1a[i] = (__bf16)v;
            } else if (i < 6144) {
                int q = i - 2048;
                int mk = q >> 9, lane = (q >> 3) & 63, j = q & 7;
                int m = mk >> 1, kt = mk & 1;
                int k = kt * 32 + (lane >> 4) * 8 + j, ch = m * 16 + (lane & 15);
                w2a[q] = (__bf16)fw2[k * 64 + ch];
            } else if (i < 36864) {
                int q = i - 6144;
                int tmk = q >> 9, lane = (q >> 3) & 63, j = q & 7;
                int kt = tmk & 1, tm = tmk >> 1;
                int t = tm / 3, m = tm - t * 3;
                int k = kt * 32 + (lane >> 4) * 8 + j, ch = m * 16 + (lane & 15);
                int l = ch >> 4, o = ch & 15;
                float s = 0.f;
#pragma unroll
                for (int c = 0; c < 8; ++c)
                    s += s_ai[t * 8 + c] * fw3[k * 384 + l * 128 + c * 16 + o];
                w3ta[q] = (__bf16)s;
            } else {
                int q2 = i - 36864;
                int t = q2 / 48, ch = q2 - t * 48;
                int l = ch >> 4, o = ch & 15;
                float s = 0.f;
#pragma unroll
                for (int c = 0; c < 8; ++c)
                    s += s_ai[t * 8 + c] * fb3[l * 128 + c * 16 + o];
                b3t[q2] = s;
            }
        }
    } else {
        __shared__ int lcnt[10];
        __shared__ int gbase[10];
        if (tid < 10) lcnt[tid] = 0;
        __syncthreads();
        int e = (blockIdx.x - 64) * 256 + tid;
        int t = 0, lr = 0;
        bool valid = e < NE;
        if (valid) {
            rdst[e] = atomicAdd(&cnt_dst[edst[e]], 1);
            t = A[esrc[e]];
            lr = atomicAdd(&lcnt[t], 1);
        }
        __syncthreads();
        if (tid < 10) gbase[tid] = atomicAdd(&cnt_t[tid], lcnt[tid]);
        __syncthreads();
        if (valid) rtp[e] = (t << 20) | (gbase[t] + lr);
    }
}

// ---------- alloc: CSR base per node via block scan + bump atomic (order-free) ----------
__global__ __launch_bounds__(256) void alloc_k(const int* __restrict__ cnt_dst,
                                               int* __restrict__ off_dst,
                                               int* __restrict__ bump) {
    __shared__ int s[256];
    __shared__ int sbase;
    const int tid = threadIdx.x;
    const int idx = blockIdx.x * 256 + tid;
    int c = (idx < NN) ? cnt_dst[idx] : 0;
    s[tid] = c;
    __syncthreads();
    for (int off = 1; off < 256; off <<= 1) {
        int v = (tid >= off) ? s[tid - off] : 0;
        __syncthreads();
        s[tid] += v;
        __syncthreads();
    }
    if (tid == 255) sbase = atomicAdd(bump, s[255]);
    __syncthreads();
    if (idx < NN) off_dst[idx] = sbase + s[tid] - c;
}

// ---------- scatter: tlist (type-bucketed edge ids) + elist (CSR of tlist positions) ----------
__global__ void scatter_k(const int* __restrict__ edst,
                          const int* __restrict__ off_dst,
                          const int* __restrict__ rdst, const int* __restrict__ rtp,
                          int* __restrict__ elist, int* __restrict__ tlist) {
    int e = blockIdx.x * blockDim.x + threadIdx.x;
    if (e >= NE) return;
    int rp = rtp[e];
    int p = (rp >> 20) * TCAP + (rp & 0xFFFFF);
    tlist[p] = e;
    elist[off_dst[edst[e]] + rdst[e]] = p;
}

// ---------- edge kernel: 1 wave = 64 edges; 3 MFMA GEMMs; coalesced payload (tlist order) ----------
__global__ __launch_bounds__(64) void edge_k(
    const int* __restrict__ tlist, const int* __restrict__ A,
    const int* __restrict__ esrc, const int* __restrict__ edst,
    const float* __restrict__ pos, const float* __restrict__ shifts,
    const float* __restrict__ cell, const int* __restrict__ batch,
    const __bf16* __restrict__ w1a, const __bf16* __restrict__ w2a,
    const __bf16* __restrict__ w3ta,
    const float* __restrict__ fb2, const float* __restrict__ b3t,
    _Float16* __restrict__ payload) {
    __shared__ __bf16 embuf[64 * 36];                  // 4.6 KB
    __shared__ __bf16 h1buf[16 * 72];                  // 2.3 KB
    __shared__ __bf16 h2buf[16 * 72];                  // 2.3 KB
    __shared__ __align__(16) _Float16 outbuf[64 * 72]; // 9.2 KB wave output staging
    const int lane = threadIdx.x;
    const int base = blockIdx.x * 64;
    const int e0 = tlist[base];
    if (e0 < 0) return;  // fully padded block (bucket fill is a 64-aligned prefix)
    int t_blk = __builtin_amdgcn_readfirstlane(A[esrc[e0]]);

    int eid = tlist[base + lane];
    if (eid < 0) eid = e0;  // pad lanes compute garbage rows (never read)

    // ---- geometry ----
    const int src = esrc[eid], dstn = edst[eid];
    const int b = batch[src];
    const float* cb = cell + b * 9;
    const float sh0 = shifts[eid * 3 + 0], sh1 = shifts[eid * 3 + 1], sh2 = shifts[eid * 3 + 2];
    float vx = pos[dstn * 3 + 0] - pos[src * 3 + 0] + sh0 * cb[0] + sh1 * cb[3] + sh2 * cb[6];
    float vy = pos[dstn * 3 + 1] - pos[src * 3 + 1] + sh0 * cb[1] + sh1 * cb[4] + sh2 * cb[7];
    float vz = pos[dstn * 3 + 2] - pos[src * 3 + 2] + sh0 * cb[2] + sh1 * cb[5] + sh2 * cb[8];
    const float len = sqrtf(vx * vx + vy * vy + vz * vz + 1e-12f);
    const float il = 1.0f / len;
    // u -> staging row [halves 48..53 as 3 f32]
    float* uo = (float*)&outbuf[lane * 72 + 48];
    uo[0] = vx * il; uo[1] = vy * il; uo[2] = vz * il;

    // ---- radial basis row (K=32; k=8 -> 1.0 folds bias) ----
    bf16x8 er0;
#pragma unroll
    for (int k = 0; k < 8; ++k) {
        float d = (len - (5.0f * (float)(k + 1) / 9.0f)) * 1.8f;
        er0[k] = (__bf16)(__expf(-d * d) * 2.525381361380528f);  // sqrt(8)/1.12
    }
    bf16x8 er1 = {};
    er1[0] = (__bf16)1.0f;
    bf16x8 zz = {};
    *(bf16x8*)&embuf[lane * 36 + 0]  = er0;
    *(bf16x8*)&embuf[lane * 36 + 8]  = er1;
    *(bf16x8*)&embuf[lane * 36 + 16] = zz;
    *(bf16x8*)&embuf[lane * 36 + 24] = zz;

    // ---- A-fragments (weights) + biases ----
    bf16x8 a1[4], a2[8], a3[6];
#pragma unroll
    for (int m = 0; m < 4; ++m) a1[m] = *(const bf16x8*)(w1a + (m * 64 + lane) * 8);
#pragma unroll
    for (int i = 0; i < 8; ++i) a2[i] = *(const bf16x8*)(w2a + (i * 64 + lane) * 8);
#pragma unroll
    for (int i = 0; i < 6; ++i)
        a3[i] = *(const bf16x8*)(w3ta + ((size_t)(t_blk * 6 + i) * 64 + lane) * 8);
    const int qr = (lane >> 4) * 4;
    const int q8 = (lane >> 4) * 8;
    f32x4 bias2[4], bias3[3];
#pragma unroll
    for (int m = 0; m < 4; ++m) bias2[m] = *(const f32x4*)(fb2 + m * 16 + qr);
#pragma unroll
    for (int m = 0; m < 3; ++m) bias3[m] = *(const f32x4*)(b3t + t_blk * 48 + m * 16 + qr);
    __syncthreads();

    const float SC = (float)NN / (float)NE;  // 1/16
    const int colrow = lane & 15;
#pragma unroll 1
    for (int n = 0; n < 4; ++n) {
        const int erow = n * 16 + colrow;
        // GEMM1: h1 = silu(emb @ W1 + b1)
        bf16x8 b1 = *(bf16x8*)&embuf[erow * 36 + q8];
#pragma unroll
        for (int m = 0; m < 4; ++m) {
            f32x4 c = {0.f, 0.f, 0.f, 0.f};
            c = __builtin_amdgcn_mfma_f32_16x16x32_bf16(a1[m], b1, c, 0, 0, 0);
            __bf16 hp[4];
#pragma unroll
            for (int r = 0; r < 4; ++r) hp[r] = (__bf16)silu_f(c[r]);
            *(uint2*)&h1buf[colrow * 72 + m * 16 + qr] = *(uint2*)hp;
        }
        __syncthreads();
        // GEMM2: h2 = silu(h1 @ W2 + b2)
        bf16x8 b20 = *(bf16x8*)&h1buf[colrow * 72 + q8];
        bf16x8 b21 = *(bf16x8*)&h1buf[colrow * 72 + 32 + q8];
#pragma unroll
        for (int m = 0; m < 4; ++m) {
            f32x4 c = bias2[m];
            c = __builtin_amdgcn_mfma_f32_16x16x32_bf16(a2[m * 2 + 0], b20, c, 0, 0, 0);
            c = __builtin_amdgcn_mfma_f32_16x16x32_bf16(a2[m * 2 + 1], b21, c, 0, 0, 0);
            __bf16 hp[4];
#pragma unroll
            for (int r = 0; r < 4; ++r) hp[r] = (__bf16)silu_f(c[r]);
            *(uint2*)&h2buf[colrow * 72 + m * 16 + qr] = *(uint2*)hp;
        }
        __syncthreads();
        // GEMM3: s = (h2 @ W3t + b3t) * SC -> fp16 into wave staging buffer
        bf16x8 b30 = *(bf16x8*)&h2buf[colrow * 72 + q8];
        bf16x8 b31 = *(bf16x8*)&h2buf[colrow * 72 + 32 + q8];
#pragma unroll
        for (int m = 0; m < 3; ++m) {
            f32x4 c = bias3[m];
            c = __builtin_amdgcn_mfma_f32_16x16x32_bf16(a3[m * 2 + 0], b30, c, 0, 0, 0);
            c = __builtin_amdgcn_mfma_f32_16x16x32_bf16(a3[m * 2 + 1], b31, c, 0, 0, 0);
            f16x4 hp;
#pragma unroll
            for (int r = 0; r < 4; ++r) hp[r] = (_Float16)(c[r] * SC);
            *(f16x4*)&outbuf[(erow)*72 + m * 16 + qr] = hp;
        }
        __syncthreads();
    }

    // ---- flush wave's 64 rows fully coalesced: 8 x dwordx4 per lane ----
#pragma unroll
    for (int q = 0; q < 8; ++q) {
        int cidx = q * 64 + lane;
        int row = cidx >> 3, off = cidx & 7;
        uint4 v = *(const uint4*)&outbuf[row * 72 + off * 8];
        *(uint4*)(payload + ((size_t)(base + row)) * PLH + off * 8) = v;
    }
}

// ---------- gather: elist-indirected 128B rows -> factor-table expansion -> out ----------
__global__ __launch_bounds__(256) void gather_k(const int* __restrict__ off_dst,
                                                const int* __restrict__ cnt_dst,
                                                const int* __restrict__ elist,
                                                const _Float16* __restrict__ payload,
                                                float* __restrict__ out) {
    __shared__ int spid[GROWS];
    __shared__ __align__(16) _Float16 sp_s[GROWS][72];
    __shared__ float sfac[GROWS][16];
    const int n = blockIdx.x;
    const int tid = threadIdx.x;
    const int lo = off_dst[n];
    const int cnt = cnt_dst[n];
    int voff = 0, foff = 0;
    if (tid < 16) { voff = tid; foff = 0; }
    else if (tid < 64) { int q = tid - 16; voff = 16 + q / 3; foff = 1 + q % 3; }
    else if (tid < 208) { int q = tid - 64; voff = 32 + q / 9; foff = 4 + q % 9; }
    float acc = 0.f;
    for (int p0 = 0; p0 < cnt; p0 += GROWS) {
        const int m = min(GROWS, cnt - p0);
        if (tid < m) spid[tid] = elist[lo + p0 + tid];
        __syncthreads();
        if (tid < m * 8) {
            int r = tid >> 3, q = tid & 7;
            ((uint4*)&sp_s[r][0])[q] = ((const uint4*)(payload + (size_t)spid[r] * PLH))[q];
        }
        __syncthreads();
        for (int idx = tid; idx < m * 16; idx += 256) {
            int r = idx >> 4, f = idx & 15;
            if (f < 13) {
                const float* uf = (const float*)&sp_s[r][48];
                float v;
                if (f == 0) v = 1.0f;
                else if (f < 4) v = uf[f - 1];
                else { int g = f - 4; v = uf[g / 3] * uf[g % 3]; }
                sfac[r][f] = v;
            }
        }
        __syncthreads();
        if (tid < 208)
            for (int r = 0; r < m; ++r)
                acc += (float)sp_s[r][voff] * sfac[r][foff];
        __syncthreads();
    }
    if (tid < 208) {
        out[(size_t)n * TD + tid] = acc;
        out[(size_t)n * TD + 208 + tid] = 0.f;
    }
}

extern "C" void kernel_launch(void* const* d_in, const int* in_sizes, int n_in,
                              void* d_out, int out_size, void* d_ws, size_t ws_size,
                              hipStream_t stream) {
    const float* pos       = (const float*)d_in[0];
    const int*   A         = (const int*)d_in[1];
    const int*   batch     = (const int*)d_in[2];
    const int*   esrc      = (const int*)d_in[3];
    const int*   edst      = (const int*)d_in[4];
    const float* shifts    = (const float*)d_in[5];
    const float* cell      = (const float*)d_in[6];
    const float* emb_table = (const float*)d_in[7];
    const float* aw1       = (const float*)d_in[8];
    const float* ab1       = (const float*)d_in[9];
    const float* aw2       = (const float*)d_in[10];
    const float* ab2       = (const float*)d_in[11];
    const float* fw1       = (const float*)d_in[12];
    const float* fb1       = (const float*)d_in[13];
    const float* fw2       = (const float*)d_in[14];
    const float* fb2       = (const float*)d_in[15];
    const float* fw3       = (const float*)d_in[16];
    const float* fb3       = (const float*)d_in[17];
    float* out = (float*)d_out;

    // ---- ws layout (bytes from base) ----
    char* base = (char*)d_ws;
    __bf16* w1a    = (__bf16*)(base + 0);        // 4096 B
    __bf16* w2a    = (__bf16*)(base + 4096);     // 8192 B
    __bf16* w3ta   = (__bf16*)(base + 12288);    // 61440 B
    float*  b3t    = (float*)(base + 73728);     // 1920 B -> ends 75648
    int* cnt_dst   = (int*)(base + 75648);       // 25008*4 -> 175680
    int* cnt_t     = (int*)(base + 175680);      // 64 B
    int* bump      = (int*)(base + 175744);      // 64 B
    int* off_dst   = (int*)(base + 175808);      // 25008*4 -> 275840
    int* rdst      = (int*)(base + 275840);      // 1.6 MB
    int* rtp       = (int*)(base + 1875840);     // 1.6 MB
    int* elist     = (int*)(base + 3475840);     // 1.6 MB
    int* tlist     = (int*)(base + 5075840);     // 460800*4 = 1843200 -> 6919040
    _Float16* payload = (_Float16*)(base + 6919168);  // 460800*128 B = 59.0 MB

    hipMemsetAsync(cnt_dst, 0, 100160, stream);        // cnt_dst + cnt_t + bump
    hipMemsetAsync(tlist, 0xFF, NROWS * 4, stream);    // bucket pads = -1
    prep_count_k<<<64 + (NE + 255) / 256, 256, 0, stream>>>(
        emb_table, aw1, ab1, aw2, ab2, fw1, fb1, fw2, fw3, fb3,
        w1a, w2a, w3ta, b3t, esrc, edst, A, cnt_dst, cnt_t, rdst, rtp);
    alloc_k<<<(NN + 255) / 256, 256, 0, stream>>>(cnt_dst, off_dst, bump);
    scatter_k<<<(NE + 255) / 256, 256, 0, stream>>>(edst, off_dst, rdst, rtp, elist, tlist);
    edge_k<<<NROWS / 64, 64, 0, stream>>>(tlist, A, esrc, edst, pos, shifts, cell, batch,
                                          w1a, w2a, w3ta, fb2, b3t, payload);
    gather_k<<<NN, 256, 0, stream>>>(off_dst, cnt_dst, elist, payload, out);
}